// Round 1
// baseline (117.038 us; speedup 1.0000x reference)
//
#include <hip/hip_runtime.h>

// TuckERInteraction: scores[n'] = sum_i u[n',i] * v[n',i]
//   v[n',i] = sum_j W[n'>>8, i, j] * t_bn[n', j]        (stage A, grouped by k = n'>>8)
//   u[n',i] = sum_a h_bn[n',a] * r[(n'&255)*128+a, i]   (stage B, grouped by low = n'&255)
// N = 32768, D = 128. Only V is materialized (bf16, 8 MB in d_ws).
//
// R5: occupancy fix. Previous version ran grid=256 (1 block/CU, 1 wave/SIMD) —
// minimum occupancy; staging latency fully exposed, ~5x off BW roofline.
// Now 512 blocks per stage (64 rows each), LDS 52.2 KB -> 2 resident
// blocks/CU so staging of one block overlaps MFMA of the other. Chunked XCD
// swizzle co-locates sibling blocks (same W[k] / same r[low]) on one XCD's L2.
// setprio(1) around the MFMA phase (resident blocks now have role diversity).

typedef __attribute__((ext_vector_type(8))) short bf16x8;   // MFMA A/B fragment (8 bf16)
typedef __attribute__((ext_vector_type(4))) short s16x4;
typedef __attribute__((ext_vector_type(4))) float f32x4;

#define DPAD 136   // LDS row stride (elements)
#define BN_EPS 1e-5f

__device__ inline unsigned short f2bf(float f) {
  unsigned u = __builtin_bit_cast(unsigned, f);
  u += 0x7FFFu + ((u >> 16) & 1u);          // round-to-nearest-even
  return (unsigned short)(u >> 16);
}
__device__ inline float bf2f(unsigned short h) {
  unsigned u = ((unsigned)h) << 16;
  return __builtin_bit_cast(float, u);
}
__device__ inline unsigned pack2bf(float lo, float hi) {
  return (unsigned)f2bf(lo) | ((unsigned)f2bf(hi) << 16);
}

// Chunked XCD remap for nwg=512 (512%8==0 -> bijective). HW round-robins
// consecutive blockIdx across the 8 XCDs; remap so each XCD owns a
// contiguous 64-block chunk -> the 4 quarters of one k (stage A) / the 2
// halves of one low (stage B) share that XCD's L2.
__device__ inline int xcd_map(int bid) { return (bid & 7) * 64 + (bid >> 3); }

// ---------------- Stage A: V[n', i] = sum_j W[k,i,j] * t_bn[n', j] ----------------
// grid 512: block = (k, quarter); 64 rows n' = k*256 + quarter*64 + m
__global__ __launch_bounds__(256, 2) void k_stageA(
    const float* __restrict__ t, const float* __restrict__ W,
    const float* __restrict__ gamma1, const float* __restrict__ beta1,
    const float* __restrict__ mean1, const float* __restrict__ var1,
    unsigned short* __restrict__ V) {
  __shared__ short LA[64 * DPAD];   // Tl[m][j] = bf16(t_bn[rowbase+m, j])
  __shared__ short LB[128 * DPAD];  // Wl[i][j] = bf16(W[k, i, j])
  const int tid = threadIdx.x;
  const int c = tid & 31;
  const int rr = tid >> 5;
  const int wv_ = tid >> 6;
  const int lane = tid & 63;
  const int l16 = lane & 15;
  const int quad = lane >> 4;

  const int wg = xcd_map(blockIdx.x);
  const int k = wg >> 2;            // [0,128)
  const int quarter = wg & 3;
  const int rowbase = k * 256 + quarter * 64;

  f32x4 g  = *(const f32x4*)(gamma1 + c * 4);
  f32x4 be = *(const f32x4*)(beta1  + c * 4);
  f32x4 mu = *(const f32x4*)(mean1  + c * 4);
  f32x4 va = *(const f32x4*)(var1   + c * 4);
  f32x4 sc, bi;
  for (int q = 0; q < 4; ++q) {
    sc[q] = g[q] * rsqrtf(va[q] + BN_EPS);
    bi[q] = be[q] - mu[q] * sc[q];
  }
  const float* tbase = t + (size_t)rowbase * 128;
  const float* wbase = W + (size_t)k * 16384;
#pragma unroll
  for (int it = 0; it < 8; ++it) {
    const int m = it * 8 + rr;
    f32x4 tv = *(const f32x4*)(tbase + m * 128 + c * 4);
    s16x4 tb;
    for (int q = 0; q < 4; ++q) tb[q] = (short)f2bf(tv[q] * sc[q] + bi[q]);
    *(s16x4*)(&LA[m * DPAD + c * 4]) = tb;
  }
#pragma unroll
  for (int it = 0; it < 16; ++it) {
    const int m = it * 8 + rr;
    f32x4 wvv = *(const f32x4*)(wbase + m * 128 + c * 4);
    s16x4 wb;
    for (int q = 0; q < 4; ++q) wb[q] = (short)f2bf(wvv[q]);
    *(s16x4*)(&LB[m * DPAD + c * 4]) = wb;
  }
  __syncthreads();

  f32x4 acc[8];
#pragma unroll
  for (int nt = 0; nt < 8; ++nt) acc[nt] = (f32x4){0.f, 0.f, 0.f, 0.f};

  // swapped operands: acc = mfma(Wfrag, Tfrag) -> D[i-part(row), n'-part(col)]
  __builtin_amdgcn_s_setprio(1);
#pragma unroll
  for (int ks = 0; ks < 4; ++ks) {
    const int K0 = ks * 32 + quad * 8;
    bf16x8 a = *(const bf16x8*)(&LA[(wv_ * 16 + l16) * DPAD + K0]);
    bf16x8 b[8];
#pragma unroll
    for (int nt = 0; nt < 8; ++nt)
      b[nt] = *(const bf16x8*)(&LB[(nt * 16 + l16) * DPAD + K0]);
#pragma unroll
    for (int nt = 0; nt < 8; ++nt)
      acc[nt] = __builtin_amdgcn_mfma_f32_16x16x32_bf16(b[nt], a, acc[nt], 0, 0, 0);
  }
  __builtin_amdgcn_s_setprio(0);

  // lane holds i = nt*16 + quad*4 + {0..3} of row n' = rowbase + wv*16 + l16
  const size_t np = (size_t)(rowbase + wv_ * 16 + l16) * 128;
#pragma unroll
  for (int nt = 0; nt < 8; ++nt) {
    unsigned two[2];
    two[0] = pack2bf(acc[nt][0], acc[nt][1]);
    two[1] = pack2bf(acc[nt][2], acc[nt][3]);
    *(uint2*)(V + np + nt * 16 + quad * 4) = *(uint2*)two;
  }
}

// ------- Stage B + dot: out[n'] = sum_i (sum_a h_bn[n',a] r[low*128+a, i]) * V[n',i] -------
// grid 512: block = (low, half); rows n' = kk*256 + low, kk = half*64 + [0,64)
__global__ __launch_bounds__(256, 2) void k_bdot(
    const float* __restrict__ h, const float* __restrict__ r,
    const float* __restrict__ gamma0, const float* __restrict__ beta0,
    const float* __restrict__ mean0, const float* __restrict__ var0,
    const unsigned short* __restrict__ V, float* __restrict__ out) {
  __shared__ short LA[64 * DPAD];   // Hl[kkloc][a] = bf16(h_bn[(half*64+kkloc)*256+low, a])
  __shared__ short LB[128 * DPAD];  // Rl[i][a]  = bf16(r[low*128+a, i])   (transposed)
  const int tid = threadIdx.x;
  const int c = tid & 31;
  const int rr = tid >> 5;
  const int wv_ = tid >> 6;
  const int lane = tid & 63;
  const int l16 = lane & 15;
  const int quad = lane >> 4;

  const int wg = xcd_map(blockIdx.x);
  const int low = wg >> 1;          // [0,256)
  const int half = wg & 1;
  const int kkbase = half * 64;

  f32x4 g  = *(const f32x4*)(gamma0 + c * 4);
  f32x4 be = *(const f32x4*)(beta0  + c * 4);
  f32x4 mu = *(const f32x4*)(mean0  + c * 4);
  f32x4 va = *(const f32x4*)(var0   + c * 4);
  f32x4 sc, bi;
  for (int q = 0; q < 4; ++q) {
    sc[q] = g[q] * rsqrtf(va[q] + BN_EPS);
    bi[q] = be[q] - mu[q] * sc[q];
  }
#pragma unroll
  for (int it = 0; it < 8; ++it) {
    const int kkloc = it * 8 + rr;
    f32x4 hv = *(const f32x4*)(h + ((size_t)(kkbase + kkloc) * 256 + low) * 128 + c * 4);
    s16x4 hb;
    for (int q = 0; q < 4; ++q) hb[q] = (short)f2bf(hv[q] * sc[q] + bi[q]);
    *(s16x4*)(&LA[kkloc * DPAD + c * 4]) = hb;
  }
  // transpose-stage r: thread owns 4x4 block (rows a0..a0+3, cols 4c..4c+3)
#pragma unroll
  for (int it = 0; it < 4; ++it) {
    const int a0 = it * 32 + rr * 4;
    f32x4 rv[4];
    for (int v = 0; v < 4; ++v)
      rv[v] = *(const f32x4*)(r + ((size_t)(low * 128 + a0 + v)) * 128 + c * 4);
    for (int u = 0; u < 4; ++u) {
      s16x4 w;
      for (int v = 0; v < 4; ++v) w[v] = (short)f2bf(rv[v][u]);
      *(s16x4*)(&LB[(c * 4 + u) * DPAD + a0]) = w;
    }
  }
  __syncthreads();

  f32x4 acc[8];
#pragma unroll
  for (int nt = 0; nt < 8; ++nt) acc[nt] = (f32x4){0.f, 0.f, 0.f, 0.f};

  // swapped operands: acc = mfma(Rfrag, Hfrag) -> D[i-part(row), kk-part(col)]
  __builtin_amdgcn_s_setprio(1);
#pragma unroll
  for (int ks = 0; ks < 4; ++ks) {
    const int K0 = ks * 32 + quad * 8;
    bf16x8 a = *(const bf16x8*)(&LA[(wv_ * 16 + l16) * DPAD + K0]);
    bf16x8 b[8];
#pragma unroll
    for (int nt = 0; nt < 8; ++nt)
      b[nt] = *(const bf16x8*)(&LB[(nt * 16 + l16) * DPAD + K0]);
#pragma unroll
    for (int nt = 0; nt < 8; ++nt)
      acc[nt] = __builtin_amdgcn_mfma_f32_16x16x32_bf16(b[nt], a, acc[nt], 0, 0, 0);
  }
  __builtin_amdgcn_s_setprio(0);

  // fused dot: lane holds u[n', i=nt*16+quad*4+q] fp32 for row n' = kk*256+low,
  // kk = kkbase + wv*16 + l16. Load matching V bf16, FMA, reduce across quads.
  const int kk = kkbase + wv_ * 16 + l16;
  const size_t np = ((size_t)kk * 256 + low) * 128;
  float s = 0.f;
#pragma unroll
  for (int nt = 0; nt < 8; ++nt) {
    const uint2 vv = *(const uint2*)(V + np + nt * 16 + quad * 4);
    s += acc[nt][0] * bf2f((unsigned short)(vv.x & 0xFFFFu));
    s += acc[nt][1] * bf2f((unsigned short)(vv.x >> 16));
    s += acc[nt][2] * bf2f((unsigned short)(vv.y & 0xFFFFu));
    s += acc[nt][3] * bf2f((unsigned short)(vv.y >> 16));
  }
  s += __shfl_xor(s, 16, 64);
  s += __shfl_xor(s, 32, 64);
  if (quad == 0) out[(size_t)kk * 256 + low] = s;
}

extern "C" void kernel_launch(void* const* d_in, const int* in_sizes, int n_in,
                              void* d_out, int out_size, void* d_ws, size_t ws_size,
                              hipStream_t stream) {
  const float* h      = (const float*)d_in[0];
  const float* r      = (const float*)d_in[1];
  const float* t      = (const float*)d_in[2];
  const float* W      = (const float*)d_in[3];
  const float* gamma0 = (const float*)d_in[4];
  const float* beta0  = (const float*)d_in[5];
  const float* mean0  = (const float*)d_in[6];
  const float* var0   = (const float*)d_in[7];
  const float* gamma1 = (const float*)d_in[8];
  const float* beta1  = (const float*)d_in[9];
  const float* mean1  = (const float*)d_in[10];
  const float* var1   = (const float*)d_in[11];
  float* out = (float*)d_out;

  unsigned short* V = (unsigned short*)d_ws;   // 32768*128 bf16 = 8 MB

  k_stageA<<<512, 256, 0, stream>>>(t, W, gamma1, beta1, mean1, var1, V);
  k_bdot<<<512, 256, 0, stream>>>(h, r, gamma0, beta0, mean0, var0, V, out);
}